// Round 12
// baseline (307.532 us; speedup 1.0000x reference)
//
#include <hip/hip_runtime.h>

// Problem constants (B=1)
#define NN 1024     // nodes
#define NE 4096     // edges
#define FVD 512
#define FED 64
#define NHD 256
#define FOUTD 250
#define ICAP 64     // max incident edges per node (E[deg]=8, Poisson tail safe)
#define VCAP 64     // max off-diag nnz per adj_v row
#define ECAP 128    // max off-diag nnz per adj_e row (E[adj]~16)

// ---------------------------------------------------------------------------
// 0) Fused init: se/te/icnt init + pad w3 + zero GEMM outputs + v1 = Z @ p1
//    Grid: 1024 x 256 = 262144 threads = 4096 waves (one wave per edge for v1).
__global__ __launch_bounds__(256) void init_fused(
    const float* __restrict__ Z, const float* __restrict__ p1,
    const float* __restrict__ w3,
    int* __restrict__ se, int* __restrict__ te, int* __restrict__ icnt,
    float* __restrict__ w3p, float4* __restrict__ HW1z,
    float4* __restrict__ ZW2z, float4* __restrict__ XW3pz,
    float* __restrict__ v1) {
  int gtid = blockIdx.x * 256 + threadIdx.x;
  // v1: one wave per edge, lane = feature (FED == 64)
  int wid = gtid >> 6, lane = gtid & 63;
  if (wid < NE) {
    float val = Z[(size_t)wid * FED + lane] * p1[lane];
    for (int off = 32; off; off >>= 1) val += __shfl_down(val, off);
    if (lane == 0) v1[wid] = val;
  }
  if (gtid < NE) { se[gtid] = 0x7fffffff; te[gtid] = -1; }
  if (gtid < NN) icnt[gtid] = 0;
  if (gtid < 256 * 256) {            // pad w3 (256x250 -> 256x256)
    int r = gtid >> 8, c = gtid & 255;
    w3p[gtid] = (c < FOUTD) ? w3[r * FOUTD + c] : 0.f;
  }
  const float4 z4 = make_float4(0.f, 0.f, 0.f, 0.f);
  if (gtid < 65536)  HW1z[gtid] = z4;     // 1024*256 floats
  if (gtid < 131072) ZW2z[gtid] = z4;     // 4096*128 floats
  if (gtid < 65536)  XW3pz[gtid] = z4;    // 1024*256 floats
}

// ---------------------------------------------------------------------------
// 1a) Scan all of T in parallel: one thread per (n,e) entry, coalesced along e.
__global__ __launch_bounds__(256) void scan_T(
    const float* __restrict__ T, int* __restrict__ se, int* __restrict__ te) {
  size_t i = (size_t)blockIdx.x * blockDim.x + threadIdx.x;   // i = n*NE + e
  if (i >= (size_t)NN * NE) return;
  float v = T[i];
  if (v > 0.5f) {
    int n = (int)(i >> 12);        // / NE
    int e = (int)(i & (NE - 1));   // % NE
    atomicMin(&se[e], n);
    atomicMax(&te[e], n);
  }
}

// 1b) Build node->edge incidence lists from endpoints.
__global__ __launch_bounds__(256) void build_inc(
    int* __restrict__ se, int* __restrict__ te,
    int* __restrict__ inc, int* __restrict__ icnt) {
  int e = blockIdx.x * blockDim.x + threadIdx.x;
  if (e >= NE) return;
  int s = se[e], t = te[e];
  if (s < 0 || s >= NN) { s = 0; se[e] = 0; }   // defensive
  if (t < 0 || t >= NN) { t = s; te[e] = s; }
  int p = atomicAdd(&icnt[s], 1);
  if (p < ICAP) inc[s * ICAP + p] = e;
  if (t != s) {
    p = atomicAdd(&icnt[t], 1);
    if (p < ICAP) inc[t * ICAP + p] = e;
  }
}

// ---------------------------------------------------------------------------
// 2) Ballot-compact one dense adjacency row into fixed-capacity CSR (wave-wide).
__device__ __forceinline__ void compact_row(
    const float* __restrict__ A, int wid, int lane, int C, int cap,
    int* __restrict__ cols, float* __restrict__ vals,
    float* __restrict__ diag, int* __restrict__ cnt) {
  const float4* row = (const float4*)(A + (size_t)wid * C);  // C % 4 == 0
  int base = 0;
  for (int c0 = 0; c0 < C; c0 += 256) {                      // 256 cols/wave/iter
    float4 v4 = row[(c0 >> 2) + lane];
    float vv[4] = {v4.x, v4.y, v4.z, v4.w};
    #pragma unroll
    for (int j = 0; j < 4; j++) {
      int c = c0 + lane * 4 + j;
      float v = vv[j];
      if (c == wid) diag[wid] = v;
      bool pred = (v != 0.0f) && (c != wid);
      unsigned long long m = __ballot(pred);
      if (pred) {
        int idx = base + __popcll(m & ((1ull << lane) - 1ull));
        if (idx < cap) {
          cols[(size_t)wid * cap + idx] = c;
          vals[(size_t)wid * cap + idx] = v;
        }
      }
      base += __popcll(m);
    }
  }
  if (lane == 0) cnt[wid] = base < cap ? base : cap;
}

// One kernel for both adjacency matrices: waves [0,NN) -> adjV, [NN,NN+NE) -> adjE.
__global__ void compact_both(
    const float* __restrict__ adjV, const float* __restrict__ adjE,
    int* __restrict__ avc, float* __restrict__ avv, float* __restrict__ avd,
    int* __restrict__ avcnt,
    int* __restrict__ aec, float* __restrict__ aev, float* __restrict__ aed,
    int* __restrict__ aecnt) {
  int gw = (blockIdx.x * blockDim.x + threadIdx.x) >> 6;
  int lane = threadIdx.x & 63;
  if (gw < NN) {
    compact_row(adjV, gw, lane, NN, VCAP, avc, avv, avd, avcnt);
  } else if (gw < NN + NE) {
    compact_row(adjE, gw - NN, lane, NE, ECAP, aec, aev, aed, aecnt);
  }
}

// ---------------------------------------------------------------------------
// 3) Register-blocked LDS-free split-K GEMM, atomic accumulation into zeroed C.
//    C[m][n] += (RELU_A?relu(A):A)[m, ks-slice] @ B[ks-slice, n]
template <bool RELU_A, int N4, int KK, int KSPLIT>
__global__ __launch_bounds__(256) void gemm_f4_atomic(
    const float* __restrict__ A, const float* __restrict__ B,
    float* __restrict__ C, int M) {
  constexpr int RPT = 4;
  constexpr int RG = 256 / N4;          // row-groups per block
  constexpr int KPS = KK / KSPLIT;      // k per slice
  int tid = threadIdx.x;
  int c4 = tid % N4;
  int rg = tid / N4;
  int ks = blockIdx.y;
  int m0 = blockIdx.x * (RG * RPT) + rg * RPT;
  const float4* B4 = (const float4*)B;
  float4 acc[RPT];
  #pragma unroll
  for (int r = 0; r < RPT; r++) acc[r] = make_float4(0.f, 0.f, 0.f, 0.f);
  int kbeg = ks * KPS;
  #pragma unroll 4
  for (int kc = 0; kc < KPS; kc += 4) {
    int k = kbeg + kc;
    float4 b0 = B4[(size_t)(k + 0) * N4 + c4];
    float4 b1 = B4[(size_t)(k + 1) * N4 + c4];
    float4 b2 = B4[(size_t)(k + 2) * N4 + c4];
    float4 b3 = B4[(size_t)(k + 3) * N4 + c4];
    #pragma unroll
    for (int r = 0; r < RPT; r++) {
      float4 a = *(const float4*)(A + (size_t)(m0 + r) * KK + k);
      if (RELU_A) {
        a.x = fmaxf(a.x, 0.f); a.y = fmaxf(a.y, 0.f);
        a.z = fmaxf(a.z, 0.f); a.w = fmaxf(a.w, 0.f);
      }
      acc[r].x += a.x * b0.x; acc[r].y += a.x * b0.y; acc[r].z += a.x * b0.z; acc[r].w += a.x * b0.w;
      acc[r].x += a.y * b1.x; acc[r].y += a.y * b1.y; acc[r].z += a.y * b1.z; acc[r].w += a.y * b1.w;
      acc[r].x += a.z * b2.x; acc[r].y += a.z * b2.y; acc[r].z += a.z * b2.z; acc[r].w += a.z * b2.w;
      acc[r].x += a.w * b3.x; acc[r].y += a.w * b3.y; acc[r].z += a.w * b3.z; acc[r].w += a.w * b3.w;
    }
  }
  #pragma unroll
  for (int r = 0; r < RPT; r++) {
    float* o = C + ((size_t)(m0 + r) * N4 + c4) * 4;
    atomicAdd(o + 0, acc[r].x);
    atomicAdd(o + 1, acc[r].y);
    atomicAdd(o + 2, acc[r].z);
    atomicAdd(o + 3, acc[r].w);
  }
}

// ---------------------------------------------------------------------------
// 4) Node layer apply (+ optional fused dot vout[n] = out_row . pvec)
template <bool RELU, bool FUSE>
__global__ __launch_bounds__(256) void node_apply(
    const float* __restrict__ HW, int H, int ldH, const float* __restrict__ v,
    const int* __restrict__ se, const int* __restrict__ te,
    const int* __restrict__ inc, const int* __restrict__ icnt,
    const int* __restrict__ avc, const float* __restrict__ avv,
    const float* __restrict__ avd, const int* __restrict__ avcnt,
    const float* __restrict__ bias, float* __restrict__ out,
    const float* __restrict__ pvec, float* __restrict__ vout) {
  int n = blockIdx.x;
  __shared__ float scoef[VCAP];
  __shared__ int scol[VCAP];
  __shared__ float red[256];
  int cnt = avcnt[n];
  int tid = threadIdx.x;
  if (tid < cnt) {
    int m = avc[n * VCAP + tid];
    float mult = 0.0f;
    int ic = icnt[n]; if (ic > ICAP) ic = ICAP;
    for (int k = 0; k < ic; k++) {
      int e = inc[n * ICAP + k];
      int s = se[e], t = te[e];
      float wn = (float)((s == n) + (t == n));
      float wm = (float)((s == m) + (t == m));
      mult += wn * v[e] * wm;
    }
    scoef[tid] = mult * avv[n * VCAP + tid];
    scol[tid] = m;
  }
  __syncthreads();
  float d = avd[n];
  float part = 0.0f;
  for (int h = tid; h < H; h += 256) {
    float acc = d * HW[(size_t)n * ldH + h];
    for (int k = 0; k < cnt; k++)
      acc += scoef[k] * HW[(size_t)scol[k] * ldH + h];
    acc += bias[h];
    if (RELU) acc = fmaxf(acc, 0.0f);
    out[(size_t)n * H + h] = acc;
    if (FUSE) part += acc * pvec[h];
  }
  if (FUSE) {
    red[tid] = part;
    __syncthreads();
    for (int s = 128; s; s >>= 1) {
      if (tid < s) red[tid] += red[tid + s];
      __syncthreads();
    }
    if (tid == 0) vout[n] = red[0];
  }
}

// ---------------------------------------------------------------------------
// 5) Edge layer pass A: per-row coefficients + row max (== column max: A symmetric,
//    diag = ae[i,i] > 0 dominates implicit zeros)
__global__ __launch_bounds__(256) void edge_coef(
    const float* __restrict__ v2, const int* __restrict__ se, const int* __restrict__ te,
    const int* __restrict__ aec, const float* __restrict__ aev,
    const float* __restrict__ aed, const int* __restrict__ aecnt,
    float* __restrict__ coef, float* __restrict__ rmax) {
  int i = blockIdx.x * blockDim.x + threadIdx.x;
  if (i >= NE) return;
  int s = se[i], t = te[i];
  float vs = v2[s], vt = v2[t];
  int cnt = aecnt[i];
  float mx = aed[i];
  for (int k = 0; k < cnt; k++) {
    int j = aec[i * ECAP + k];
    int sj = se[j], tj = te[j];
    float m;
    if (s == t) {
      m = 2.0f * vs * (float)((sj == s) + (tj == s));
    } else {
      m = vs * (float)((sj == s) + (tj == s)) + vt * (float)((sj == t) + (tj == t));
    }
    float c = m * aev[i * ECAP + k];
    coef[i * ECAP + k] = c;
    mx = fmaxf(mx, c);
  }
  rmax[i] = mx;
}

// 6) Edge layer pass B (+ fused dot v3[i] = out_row . p3)
__global__ __launch_bounds__(128) void edge_apply(
    const float* __restrict__ ZW, const int* __restrict__ aec,
    const float* __restrict__ coef, const float* __restrict__ aed,
    const int* __restrict__ aecnt, const float* __restrict__ rmax,
    const float* __restrict__ bias, float* __restrict__ out,
    const float* __restrict__ p3, float* __restrict__ v3) {
  int i = blockIdx.x;
  int h = threadIdx.x;        // H == 128 == blockDim
  __shared__ float sw[ECAP];
  __shared__ int sj[ECAP];
  __shared__ float red[128];
  int cnt = aecnt[i];
  if (h < cnt) {
    int j = aec[i * ECAP + h];
    sj[h] = j;
    sw[h] = coef[i * ECAP + h] / rmax[j];
  }
  __syncthreads();
  float acc = (aed[i] / rmax[i]) * ZW[(size_t)i * 128 + h];
  for (int k = 0; k < cnt; k++)
    acc += sw[k] * ZW[(size_t)sj[k] * 128 + h];
  acc += bias[h];
  acc = fmaxf(acc, 0.0f);
  out[(size_t)i * 128 + h] = acc;
  // fused v3
  red[h] = acc * p3[h];
  __syncthreads();
  for (int s = 64; s; s >>= 1) {
    if (h < s) red[h] += red[h + s];
    __syncthreads();
  }
  if (h == 0) v3[i] = red[0];
}

// ---------------------------------------------------------------------------
extern "C" void kernel_launch(void* const* d_in, const int* in_sizes, int n_in,
                              void* d_out, int out_size, void* d_ws, size_t ws_size,
                              hipStream_t stream) {
  const float* X    = (const float*)d_in[0];
  const float* Z    = (const float*)d_in[1];
  const float* adjE = (const float*)d_in[2];
  const float* adjV = (const float*)d_in[3];
  const float* T    = (const float*)d_in[4];
  const float* w1   = (const float*)d_in[5];
  const float* p1   = (const float*)d_in[6];
  const float* b1   = (const float*)d_in[7];
  const float* w2   = (const float*)d_in[8];
  const float* p2   = (const float*)d_in[9];
  const float* b2   = (const float*)d_in[10];
  const float* w3   = (const float*)d_in[11];
  const float* p3   = (const float*)d_in[12];
  const float* b3   = (const float*)d_in[13];

  float* xout = (float*)d_out;                 // (1024, 250)
  float* zout = xout + (size_t)NN * FOUTD;     // (4096, 128)

  // workspace carve-up (256B aligned)
  char* w = (char*)d_ws;
  auto alloc = [&](size_t bytes) {
    char* p = w;
    w += (bytes + 255) & ~(size_t)255;
    return p;
  };
  int*   se    = (int*)alloc(NE * 4);
  int*   te    = (int*)alloc(NE * 4);
  int*   icnt  = (int*)alloc(NN * 4);
  int*   inc   = (int*)alloc((size_t)NN * ICAP * 4);
  int*   avc   = (int*)alloc((size_t)NN * VCAP * 4);
  float* avv   = (float*)alloc((size_t)NN * VCAP * 4);
  float* avd   = (float*)alloc(NN * 4);
  int*   avcnt = (int*)alloc(NN * 4);
  int*   aec   = (int*)alloc((size_t)NE * ECAP * 4);
  float* aev   = (float*)alloc((size_t)NE * ECAP * 4);
  float* aed   = (float*)alloc(NE * 4);
  int*   aecnt = (int*)alloc(NE * 4);
  float* coef2 = (float*)alloc((size_t)NE * ECAP * 4);
  float* rmax  = (float*)alloc(NE * 4);
  float* v1    = (float*)alloc(NE * 4);
  float* v2    = (float*)alloc(NN * 4);
  float* v3    = (float*)alloc(NE * 4);
  float* HW1   = (float*)alloc((size_t)NN * NHD * 4);        // 1 MB
  float* x1    = (float*)alloc((size_t)NN * NHD * 4);        // 1 MB
  float* ZW2   = (float*)alloc((size_t)NE * 128 * 4);        // 2 MB
  float* XW3p  = (float*)alloc((size_t)NN * 256 * 4);        // 1 MB (stride 256)
  float* w3p   = (float*)alloc(256 * 256 * 4);               // padded w3
  (void)ws_size; (void)in_sizes; (void)n_in; (void)out_size;

  // 1) fused init (memsets + w3 pad + C zeroing + v1 dot)
  init_fused<<<1024, 256, 0, stream>>>(Z, p1, w3, se, te, icnt, w3p,
                                       (float4*)HW1, (float4*)ZW2, (float4*)XW3p, v1);
  // 2-4) structure extraction
  scan_T<<<(NN * NE) / 256, 256, 0, stream>>>(T, se, te);
  build_inc<<<NE / 256, 256, 0, stream>>>(se, te, inc, icnt);
  compact_both<<<(NN + NE) * 64 / 256, 256, 0, stream>>>(
      adjV, adjE, avc, avv, avd, avcnt, aec, aev, aed, aecnt);

  // ---- layer 1 (node): HW1 += X @ w1 ; x1 = apply ; v2 fused ----
  gemm_f4_atomic<false, 64, 512, 8><<<dim3(64, 8), 256, 0, stream>>>(X, w1, HW1, NN);
  node_apply<true, true><<<NN, 256, 0, stream>>>(HW1, NHD, NHD, v1, se, te, inc, icnt,
                                                 avc, avv, avd, avcnt, b1, x1, p2, v2);

  // ---- layer 2 (edge): ZW2 += relu(Z) @ w2 ; zout = apply ; v3 fused ----
  gemm_f4_atomic<true, 32, 64, 4><<<dim3(128, 4), 256, 0, stream>>>(Z, w2, ZW2, NE);
  edge_coef<<<NE / 256, 256, 0, stream>>>(v2, se, te, aec, aev, aed, aecnt, coef2, rmax);
  edge_apply<<<NE, 128, 0, stream>>>(ZW2, aec, coef2, aed, aecnt, rmax, b2, zout, p3, v3);

  // ---- layer 3 (node): XW3p += x1 @ w3p ; xout = apply ----
  gemm_f4_atomic<false, 64, 256, 8><<<dim3(64, 8), 256, 0, stream>>>(x1, w3p, XW3p, NN);
  node_apply<false, false><<<NN, 256, 0, stream>>>(XW3p, FOUTD, 256, v3, se, te, inc, icnt,
                                                   avc, avv, avd, avcnt, b3, xout,
                                                   nullptr, nullptr);
}

// Round 15
// 248.260 us; speedup vs baseline: 1.2388x; 1.2388x over previous
//
#include <hip/hip_runtime.h>

// Problem constants (B=1)
#define NN 1024     // nodes
#define NE 4096     // edges
#define FVD 512
#define FED 64
#define NHD 256
#define FOUTD 250
#define ICAP 64     // max incident edges per node (E[deg]=8, Poisson tail safe)
#define VCAP 64     // max off-diag nnz per adj_v row
#define ECAP 128    // max off-diag nnz per adj_e row (E[adj]~16)

// ---------------------------------------------------------------------------
// 0) Fused init: se/te/icnt init + pad w3 + v1 = Z @ p1
//    Grid: 1024 x 256 = 262144 threads = 4096 waves (one wave per edge for v1).
__global__ __launch_bounds__(256) void init_fused(
    const float* __restrict__ Z, const float* __restrict__ p1,
    const float* __restrict__ w3,
    int* __restrict__ se, int* __restrict__ te, int* __restrict__ icnt,
    float* __restrict__ w3p, float* __restrict__ v1) {
  int gtid = blockIdx.x * 256 + threadIdx.x;
  // v1: one wave per edge, lane = feature (FED == 64)
  int wid = gtid >> 6, lane = gtid & 63;
  if (wid < NE) {
    float val = Z[(size_t)wid * FED + lane] * p1[lane];
    for (int off = 32; off; off >>= 1) val += __shfl_down(val, off);
    if (lane == 0) v1[wid] = val;
  }
  if (gtid < NE) { se[gtid] = 0x7fffffff; te[gtid] = -1; }
  if (gtid < NN) icnt[gtid] = 0;
  if (gtid < 256 * 256) {            // pad w3 (256x250 -> 256x256)
    int r = gtid >> 8, c = gtid & 255;
    w3p[gtid] = (c < FOUTD) ? w3[r * FOUTD + c] : 0.f;
  }
}

// ---------------------------------------------------------------------------
// 1a) Scan all of T in parallel: one thread per (n,e) entry, coalesced along e.
__global__ __launch_bounds__(256) void scan_T(
    const float* __restrict__ T, int* __restrict__ se, int* __restrict__ te) {
  size_t i = (size_t)blockIdx.x * blockDim.x + threadIdx.x;   // i = n*NE + e
  if (i >= (size_t)NN * NE) return;
  float v = T[i];
  if (v > 0.5f) {
    int n = (int)(i >> 12);        // / NE
    int e = (int)(i & (NE - 1));   // % NE
    atomicMin(&se[e], n);
    atomicMax(&te[e], n);
  }
}

// 1b) Build node->edge incidence lists from endpoints.
__global__ __launch_bounds__(256) void build_inc(
    int* __restrict__ se, int* __restrict__ te,
    int* __restrict__ inc, int* __restrict__ icnt) {
  int e = blockIdx.x * blockDim.x + threadIdx.x;
  if (e >= NE) return;
  int s = se[e], t = te[e];
  if (s < 0 || s >= NN) { s = 0; se[e] = 0; }   // defensive
  if (t < 0 || t >= NN) { t = s; te[e] = s; }
  int p = atomicAdd(&icnt[s], 1);
  if (p < ICAP) inc[s * ICAP + p] = e;
  if (t != s) {
    p = atomicAdd(&icnt[t], 1);
    if (p < ICAP) inc[t * ICAP + p] = e;
  }
}

// ---------------------------------------------------------------------------
// 2) Ballot-compact one dense adjacency row into fixed-capacity CSR (wave-wide).
__device__ __forceinline__ void compact_row(
    const float* __restrict__ A, int wid, int lane, int C, int cap,
    int* __restrict__ cols, float* __restrict__ vals,
    float* __restrict__ diag, int* __restrict__ cnt) {
  const float4* row = (const float4*)(A + (size_t)wid * C);  // C % 4 == 0
  int base = 0;
  for (int c0 = 0; c0 < C; c0 += 256) {                      // 256 cols/wave/iter
    float4 v4 = row[(c0 >> 2) + lane];
    float vv[4] = {v4.x, v4.y, v4.z, v4.w};
    #pragma unroll
    for (int j = 0; j < 4; j++) {
      int c = c0 + lane * 4 + j;
      float v = vv[j];
      if (c == wid) diag[wid] = v;
      bool pred = (v != 0.0f) && (c != wid);
      unsigned long long m = __ballot(pred);
      if (pred) {
        int idx = base + __popcll(m & ((1ull << lane) - 1ull));
        if (idx < cap) {
          cols[(size_t)wid * cap + idx] = c;
          vals[(size_t)wid * cap + idx] = v;
        }
      }
      base += __popcll(m);
    }
  }
  if (lane == 0) cnt[wid] = base < cap ? base : cap;
}

// One kernel for both adjacency matrices: waves [0,NN) -> adjV, [NN,NN+NE) -> adjE.
__global__ void compact_both(
    const float* __restrict__ adjV, const float* __restrict__ adjE,
    int* __restrict__ avc, float* __restrict__ avv, float* __restrict__ avd,
    int* __restrict__ avcnt,
    int* __restrict__ aec, float* __restrict__ aev, float* __restrict__ aed,
    int* __restrict__ aecnt) {
  int gw = (blockIdx.x * blockDim.x + threadIdx.x) >> 6;
  int lane = threadIdx.x & 63;
  if (gw < NN) {
    compact_row(adjV, gw, lane, NN, VCAP, avc, avv, avd, avcnt);
  } else if (gw < NN + NE) {
    compact_row(adjE, gw - NN, lane, NE, ECAP, aec, aev, aed, aecnt);
  }
}

// ---------------------------------------------------------------------------
// 3) Register-blocked LDS-free split-K GEMM, deterministic private partial slabs.
//    Cpart[ks][m][n] = (RELU_A?relu(A):A)[m, ks-slice] @ B[ks-slice, n]
//    NO atomics (round-12 post-mortem: atomicAdd C amplified write traffic
//    32x -> 50 us/GEMM). Round-14 post-mortem: Cpart MUST be the slab
//    (gpart), never the final C buffer -- slabs span KSPLIT x M x N4 float4.
template <bool RELU_A, int N4, int KK, int KSPLIT>
__global__ __launch_bounds__(256) void gemm_f4(
    const float* __restrict__ A, const float* __restrict__ B,
    float* __restrict__ Cpart, int M) {
  constexpr int RPT = 4;
  constexpr int RG = 256 / N4;          // row-groups per block
  constexpr int KPS = KK / KSPLIT;      // k per slice
  int tid = threadIdx.x;
  int c4 = tid % N4;
  int rg = tid / N4;
  int ks = blockIdx.y;
  int m0 = blockIdx.x * (RG * RPT) + rg * RPT;
  const float4* B4 = (const float4*)B;
  float4 acc[RPT];
  #pragma unroll
  for (int r = 0; r < RPT; r++) acc[r] = make_float4(0.f, 0.f, 0.f, 0.f);
  int kbeg = ks * KPS;
  #pragma unroll 4
  for (int kc = 0; kc < KPS; kc += 4) {
    int k = kbeg + kc;
    float4 b0 = B4[(size_t)(k + 0) * N4 + c4];
    float4 b1 = B4[(size_t)(k + 1) * N4 + c4];
    float4 b2 = B4[(size_t)(k + 2) * N4 + c4];
    float4 b3 = B4[(size_t)(k + 3) * N4 + c4];
    #pragma unroll
    for (int r = 0; r < RPT; r++) {
      float4 a = *(const float4*)(A + (size_t)(m0 + r) * KK + k);
      if (RELU_A) {
        a.x = fmaxf(a.x, 0.f); a.y = fmaxf(a.y, 0.f);
        a.z = fmaxf(a.z, 0.f); a.w = fmaxf(a.w, 0.f);
      }
      acc[r].x += a.x * b0.x; acc[r].y += a.x * b0.y; acc[r].z += a.x * b0.z; acc[r].w += a.x * b0.w;
      acc[r].x += a.y * b1.x; acc[r].y += a.y * b1.y; acc[r].z += a.y * b1.z; acc[r].w += a.y * b1.w;
      acc[r].x += a.z * b2.x; acc[r].y += a.z * b2.y; acc[r].z += a.z * b2.z; acc[r].w += a.z * b2.w;
      acc[r].x += a.w * b3.x; acc[r].y += a.w * b3.y; acc[r].z += a.w * b3.z; acc[r].w += a.w * b3.w;
    }
  }
  float4* out = (float4*)Cpart + ((size_t)ks * M + m0) * N4 + c4;
  #pragma unroll
  for (int r = 0; r < RPT; r++) out[(size_t)r * N4] = acc[r];
}

// 3b) Sum KSPLIT partial slabs: out[i] = sum_ks part[ks][i]  (float4 elems)
__global__ void reduce_part(const float4* __restrict__ part, float4* __restrict__ out,
                            int n4, int ksplit) {
  int i = blockIdx.x * blockDim.x + threadIdx.x;
  int stride = gridDim.x * blockDim.x;
  for (; i < n4; i += stride) {
    float4 s = part[i];
    for (int k = 1; k < ksplit; k++) {
      float4 p = part[(size_t)k * n4 + i];
      s.x += p.x; s.y += p.y; s.z += p.z; s.w += p.w;
    }
    out[i] = s;
  }
}

// ---------------------------------------------------------------------------
// 4) Node layer apply (+ optional fused dot vout[n] = out_row . pvec)
template <bool RELU, bool FUSE>
__global__ __launch_bounds__(256) void node_apply(
    const float* __restrict__ HW, int H, int ldH, const float* __restrict__ v,
    const int* __restrict__ se, const int* __restrict__ te,
    const int* __restrict__ inc, const int* __restrict__ icnt,
    const int* __restrict__ avc, const float* __restrict__ avv,
    const float* __restrict__ avd, const int* __restrict__ avcnt,
    const float* __restrict__ bias, float* __restrict__ out,
    const float* __restrict__ pvec, float* __restrict__ vout) {
  int n = blockIdx.x;
  __shared__ float scoef[VCAP];
  __shared__ int scol[VCAP];
  __shared__ float red[256];
  int cnt = avcnt[n];
  int tid = threadIdx.x;
  if (tid < cnt) {
    int m = avc[n * VCAP + tid];
    float mult = 0.0f;
    int ic = icnt[n]; if (ic > ICAP) ic = ICAP;
    for (int k = 0; k < ic; k++) {
      int e = inc[n * ICAP + k];
      int s = se[e], t = te[e];
      float wn = (float)((s == n) + (t == n));
      float wm = (float)((s == m) + (t == m));
      mult += wn * v[e] * wm;
    }
    scoef[tid] = mult * avv[n * VCAP + tid];
    scol[tid] = m;
  }
  __syncthreads();
  float d = avd[n];
  float part = 0.0f;
  for (int h = tid; h < H; h += 256) {
    float acc = d * HW[(size_t)n * ldH + h];
    for (int k = 0; k < cnt; k++)
      acc += scoef[k] * HW[(size_t)scol[k] * ldH + h];
    acc += bias[h];
    if (RELU) acc = fmaxf(acc, 0.0f);
    out[(size_t)n * H + h] = acc;
    if (FUSE) part += acc * pvec[h];
  }
  if (FUSE) {
    red[tid] = part;
    __syncthreads();
    for (int s = 128; s; s >>= 1) {
      if (tid < s) red[tid] += red[tid + s];
      __syncthreads();
    }
    if (tid == 0) vout[n] = red[0];
  }
}

// ---------------------------------------------------------------------------
// 5) Edge layer pass A: per-row coefficients + row max (== column max: A symmetric,
//    diag = ae[i,i] > 0 dominates implicit zeros)
__global__ __launch_bounds__(256) void edge_coef(
    const float* __restrict__ v2, const int* __restrict__ se, const int* __restrict__ te,
    const int* __restrict__ aec, const float* __restrict__ aev,
    const float* __restrict__ aed, const int* __restrict__ aecnt,
    float* __restrict__ coef, float* __restrict__ rmax) {
  int i = blockIdx.x * blockDim.x + threadIdx.x;
  if (i >= NE) return;
  int s = se[i], t = te[i];
  float vs = v2[s], vt = v2[t];
  int cnt = aecnt[i];
  float mx = aed[i];
  for (int k = 0; k < cnt; k++) {
    int j = aec[i * ECAP + k];
    int sj = se[j], tj = te[j];
    float m;
    if (s == t) {
      m = 2.0f * vs * (float)((sj == s) + (tj == s));
    } else {
      m = vs * (float)((sj == s) + (tj == s)) + vt * (float)((sj == t) + (tj == t));
    }
    float c = m * aev[i * ECAP + k];
    coef[i * ECAP + k] = c;
    mx = fmaxf(mx, c);
  }
  rmax[i] = mx;
}

// 6) Edge layer pass B (+ fused dot v3[i] = out_row . p3)
__global__ __launch_bounds__(128) void edge_apply(
    const float* __restrict__ ZW, const int* __restrict__ aec,
    const float* __restrict__ coef, const float* __restrict__ aed,
    const int* __restrict__ aecnt, const float* __restrict__ rmax,
    const float* __restrict__ bias, float* __restrict__ out,
    const float* __restrict__ p3, float* __restrict__ v3) {
  int i = blockIdx.x;
  int h = threadIdx.x;        // H == 128 == blockDim
  __shared__ float sw[ECAP];
  __shared__ int sj[ECAP];
  __shared__ float red[128];
  int cnt = aecnt[i];
  if (h < cnt) {
    int j = aec[i * ECAP + h];
    sj[h] = j;
    sw[h] = coef[i * ECAP + h] / rmax[j];
  }
  __syncthreads();
  float acc = (aed[i] / rmax[i]) * ZW[(size_t)i * 128 + h];
  for (int k = 0; k < cnt; k++)
    acc += sw[k] * ZW[(size_t)sj[k] * 128 + h];
  acc += bias[h];
  acc = fmaxf(acc, 0.0f);
  out[(size_t)i * 128 + h] = acc;
  // fused v3
  red[h] = acc * p3[h];
  __syncthreads();
  for (int s = 64; s; s >>= 1) {
    if (h < s) red[h] += red[h + s];
    __syncthreads();
  }
  if (h == 0) v3[i] = red[0];
}

// ---------------------------------------------------------------------------
extern "C" void kernel_launch(void* const* d_in, const int* in_sizes, int n_in,
                              void* d_out, int out_size, void* d_ws, size_t ws_size,
                              hipStream_t stream) {
  const float* X    = (const float*)d_in[0];
  const float* Z    = (const float*)d_in[1];
  const float* adjE = (const float*)d_in[2];
  const float* adjV = (const float*)d_in[3];
  const float* T    = (const float*)d_in[4];
  const float* w1   = (const float*)d_in[5];
  const float* p1   = (const float*)d_in[6];
  const float* b1   = (const float*)d_in[7];
  const float* w2   = (const float*)d_in[8];
  const float* p2   = (const float*)d_in[9];
  const float* b2   = (const float*)d_in[10];
  const float* w3   = (const float*)d_in[11];
  const float* p3   = (const float*)d_in[12];
  const float* b3   = (const float*)d_in[13];

  float* xout = (float*)d_out;                 // (1024, 250)
  float* zout = xout + (size_t)NN * FOUTD;     // (4096, 128)

  // workspace carve-up (256B aligned)
  char* w = (char*)d_ws;
  auto alloc = [&](size_t bytes) {
    char* p = w;
    w += (bytes + 255) & ~(size_t)255;
    return p;
  };
  int*   se    = (int*)alloc(NE * 4);
  int*   te    = (int*)alloc(NE * 4);
  int*   icnt  = (int*)alloc(NN * 4);
  int*   inc   = (int*)alloc((size_t)NN * ICAP * 4);
  int*   avc   = (int*)alloc((size_t)NN * VCAP * 4);
  float* avv   = (float*)alloc((size_t)NN * VCAP * 4);
  float* avd   = (float*)alloc(NN * 4);
  int*   avcnt = (int*)alloc(NN * 4);
  int*   aec   = (int*)alloc((size_t)NE * ECAP * 4);
  float* aev   = (float*)alloc((size_t)NE * ECAP * 4);
  float* aed   = (float*)alloc(NE * 4);
  int*   aecnt = (int*)alloc(NE * 4);
  float* coef2 = (float*)alloc((size_t)NE * ECAP * 4);
  float* rmax  = (float*)alloc(NE * 4);
  float* v1    = (float*)alloc(NE * 4);
  float* v2    = (float*)alloc(NN * 4);
  float* v3    = (float*)alloc(NE * 4);
  float* HW1   = (float*)alloc((size_t)NN * NHD * 4);        // 1 MB
  float* x1    = (float*)alloc((size_t)NN * NHD * 4);        // 1 MB
  float* ZW2   = (float*)alloc((size_t)NE * 128 * 4);        // 2 MB
  float* XW3p  = (float*)alloc((size_t)NN * 256 * 4);        // 1 MB (stride 256)
  float* w3p   = (float*)alloc(256 * 256 * 4);               // padded w3
  float* gpart = (float*)alloc((size_t)8 * NN * NHD * 4);    // 8 MB shared split-K slab
  (void)ws_size; (void)in_sizes; (void)n_in; (void)out_size;

  // 1) fused init (se/te/icnt + w3 pad + v1 dot)
  init_fused<<<1024, 256, 0, stream>>>(Z, p1, w3, se, te, icnt, w3p, v1);
  // 2-4) structure extraction
  scan_T<<<(NN * NE) / 256, 256, 0, stream>>>(T, se, te);
  build_inc<<<NE / 256, 256, 0, stream>>>(se, te, inc, icnt);
  compact_both<<<(NN + NE) * 64 / 256, 256, 0, stream>>>(
      adjV, adjE, avc, avv, avd, avcnt, aec, aev, aed, aecnt);

  // ---- layer 1 (node): HW1 = X @ w1 ; x1 = apply ; v2 fused ----
  gemm_f4<false, 64, 512, 8><<<dim3(64, 8), 256, 0, stream>>>(X, w1, gpart, NN);
  reduce_part<<<512, 256, 0, stream>>>((const float4*)gpart, (float4*)HW1,
                                       NN * NHD / 4, 8);
  node_apply<true, true><<<NN, 256, 0, stream>>>(HW1, NHD, NHD, v1, se, te, inc, icnt,
                                                 avc, avv, avd, avcnt, b1, x1, p2, v2);

  // ---- layer 2 (edge): ZW2 = relu(Z) @ w2 ; zout = apply ; v3 fused ----
  gemm_f4<true, 32, 64, 4><<<dim3(128, 4), 256, 0, stream>>>(Z, w2, gpart, NE);
  reduce_part<<<512, 256, 0, stream>>>((const float4*)gpart, (float4*)ZW2,
                                       NE * 128 / 4, 4);
  edge_coef<<<NE / 256, 256, 0, stream>>>(v2, se, te, aec, aev, aed, aecnt, coef2, rmax);
  edge_apply<<<NE, 128, 0, stream>>>(ZW2, aec, coef2, aed, aecnt, rmax, b2, zout, p3, v3);

  // ---- layer 3 (node): XW3p = x1 @ w3p ; xout = apply ----
  gemm_f4<false, 64, 256, 8><<<dim3(64, 8), 256, 0, stream>>>(x1, w3p, gpart, NN);
  reduce_part<<<512, 256, 0, stream>>>((const float4*)gpart, (float4*)XW3p,
                                       NN * 256 / 4, 8);
  node_apply<false, false><<<NN, 256, 0, stream>>>(XW3p, FOUTD, 256, v3, se, te, inc, icnt,
                                                   avc, avv, avd, avcnt, b3, xout,
                                                   nullptr, nullptr);
}